// Round 4
// baseline (223.977 us; speedup 1.0000x reference)
//
#include <hip/hip_runtime.h>

// MedSegNet texture features: 3x3 zero-padded window per (b,c,h,w):
//  contrast, energy, entropy, homogeneity -> martingale transform.
// theta=1 => M = clamp(max(f,1e-5)*exp(-0.5), 1e-4, 1e4); all feats <= 1 so
// the EXP_MAX clamp / isfinite path is dead code.
//
// R4 changes vs R3:
//  - 8 px/thread (two float4 groups): half the waves, half the halo shfls,
//    3.75 logs/px instead of 4.5.
//  - s2 = sum(v^2) - 9*m^2 instead of the 9-FMA centered loop. Note
//    contrast = (s2/9)/(s2/8) = 8/9 exactly whenever the 1e-3 std clamp
//    doesn't fire, so s2 rounding error cancels; clamp path needs
//    s2 < 8e-6 which a uniform(0,1) input never produces. s2 clamped >= 0
//    against cancellation-induced tiny negatives (sqrt(NaN) guard).
//  - stores split into two groups of 4 to cap live registers.

#define Wd 128
#define Hd 128
#define HWd 16384

typedef float v4f __attribute__((ext_vector_type(4)));

__device__ __forceinline__ float mart(float f) {
    float fc = fmaxf(f, 1e-5f);
    float M = fc * 0.60653065971263342f;   // exp(-0.5)
    return fminf(fmaxf(M, 1e-4f), 1e4f);
}

__global__ __launch_bounds__(256) void medseg_kernel(const float* __restrict__ x,
                                                     float* __restrict__ out) {
    int tid = blockIdx.x * 256 + threadIdx.x;
    int plane = tid >> 11;                // 2048 threads per 128x128 plane
    int rem = tid & 2047;
    int h = rem >> 4;                     // 16 groups-of-8 per row
    int lane15 = rem & 15;
    int w0 = lane15 << 3;

    const float* xp = x + (size_t)plane * HWd;

    // 3 rows x 8 center cols (w0..w0+7), zero-padded rows
    v4f a[3], b[3];
#pragma unroll
    for (int dr = 0; dr < 3; ++dr) {
        int hh = h + dr - 1;
        if (hh < 0 || hh >= Hd) {
            a[dr] = (v4f){0.f, 0.f, 0.f, 0.f};
            b[dr] = (v4f){0.f, 0.f, 0.f, 0.f};
        } else {
            const float* row = xp + hh * Wd + w0;
            a[dr] = *reinterpret_cast<const v4f*>(row);
            b[dr] = *reinterpret_cast<const v4f*>(row + 4);
        }
    }

    // halo columns from neighbor lanes (convergent code). 16 lanes cover one
    // row; wave-internal row seams at lanes 16/32/48 coincide with the image
    // edge masks (lane15==0 / ==15), so cross-row shfl garbage is discarded.
    float r[3][10];
#pragma unroll
    for (int dr = 0; dr < 3; ++dr) {
        float left  = __shfl_up(b[dr].w, 1);
        float right = __shfl_down(a[dr].x, 1);
        r[dr][0] = (lane15 == 0)  ? 0.f : left;
        r[dr][1] = a[dr].x; r[dr][2] = a[dr].y; r[dr][3] = a[dr].z; r[dr][4] = a[dr].w;
        r[dr][5] = b[dr].x; r[dr][6] = b[dr].y; r[dr][7] = b[dr].z; r[dr][8] = b[dr].w;
        r[dr][9] = (lane15 == 15) ? 0.f : right;
    }

    // column partial sums shared across the 8 output pixels
    float colS[10], colE[10], colN[10];
#pragma unroll
    for (int j = 0; j < 10; ++j) {
        float s = 0.f, e = 0.f, en = 0.f;
#pragma unroll
        for (int dr = 0; dr < 3; ++dr) {
            float vv = r[dr][j];
            s += vv;
            e = fmaf(vv, vv, e);
            float cl = fmaxf(vv, 1e-6f);
            en = fmaf(cl, __logf(cl), en);
        }
        colS[j] = s; colE[j] = e; colN[j] = en;
    }

    size_t base = (size_t)plane * 4 * HWd + h * Wd + w0;

#pragma unroll
    for (int half = 0; half < 2; ++half) {
        float con[4], ene[4], ent[4], hom[4];
#pragma unroll
        for (int k = 0; k < 4; ++k) {
            int i = half * 4 + k;
            float sum = colS[i] + colS[i + 1] + colS[i + 2];
            float m = sum * (1.f / 9.f);
            float E9 = colE[i] + colE[i + 1] + colE[i + 2];
            float energy = E9 * (1.f / 9.f);
            float entropy = -(colN[i] + colN[i + 1] + colN[i + 2]) * (1.f / 9.f);

            float s2 = fmaxf(fmaf(-m, sum, E9), 0.f);   // sum (v-m)^2

            float sa = 0.f;
#pragma unroll
            for (int dr = 0; dr < 3; ++dr) {
#pragma unroll
                for (int dj = 0; dj < 3; ++dj)
                    sa += fabsf(r[dr][i + dj] - m);
            }
            float var = s2 * 0.125f;                    // ddof=1 -> /8
            float sd = fmaxf(sqrtf(var), 1e-3f);
            float contrast = s2 * (1.f / 9.f) / (sd * sd);
            float homog = 1.f / ((9.f + sa) * (1.f / 9.f) + 1e-6f);

            con[k] = mart(contrast);
            ene[k] = mart(energy);
            ent[k] = mart(entropy);
            hom[k] = mart(homog);
        }
        size_t o = base + half * 4;
        __builtin_nontemporal_store((v4f){con[0], con[1], con[2], con[3]},
                                    reinterpret_cast<v4f*>(out + o));
        __builtin_nontemporal_store((v4f){ene[0], ene[1], ene[2], ene[3]},
                                    reinterpret_cast<v4f*>(out + o + HWd));
        __builtin_nontemporal_store((v4f){ent[0], ent[1], ent[2], ent[3]},
                                    reinterpret_cast<v4f*>(out + o + 2 * HWd));
        __builtin_nontemporal_store((v4f){hom[0], hom[1], hom[2], hom[3]},
                                    reinterpret_cast<v4f*>(out + o + 3 * HWd));
    }
}

extern "C" void kernel_launch(void* const* d_in, const int* in_sizes, int n_in,
                              void* d_out, int out_size, void* d_ws, size_t ws_size,
                              hipStream_t stream) {
    const float* x = (const float*)d_in[0];
    float* out = (float*)d_out;
    int n_planes = in_sizes[0] / HWd;            // B*C = 512
    int total_threads = n_planes * (HWd / 8);
    int blocks = total_threads / 256;            // exact: 4096
    medseg_kernel<<<blocks, 256, 0, stream>>>(x, out);
}

// Round 5
// 157.411 us; speedup vs baseline: 1.4229x; 1.4229x over previous
//
#include <hip/hip_runtime.h>

// MedSegNet texture features: 3x3 zero-padded window per (b,c,h,w):
//  contrast, energy, entropy, homogeneity -> martingale transform.
// theta=1 => M = clamp(max(f,1e-5)*exp(-0.5), 1e-4, 1e4); all feats <= 1 so
// the EXP_MAX clamp / isfinite path is dead code.
//
// R5: 4 px x 2 adjacent rows per thread.
//  - Store layout lesson from R4: an nt dwordx4 store must have the 32 lanes
//    of a row-group covering a CONTIGUOUS 512B segment (whole 64B lines per
//    instruction), else partial lines stream to HBM -> 2x WRITE_SIZE. Here
//    lane31*4 floats keeps every store instruction fully line-covered.
//  - Two rows share 2/4 loaded input rows and the per-element v^2 and
//    cl*log(cl) column terms: 3 logs/px (vs 4.5 in R3).

#define Wd 128
#define Hd 128
#define HWd 16384

typedef float v4f __attribute__((ext_vector_type(4)));

__device__ __forceinline__ float mart(float f) {
    float fc = fmaxf(f, 1e-5f);
    float M = fc * 0.60653065971263342f;   // exp(-0.5)
    return fminf(fmaxf(M, 1e-4f), 1e4f);
}

__global__ __launch_bounds__(256) void medseg_kernel(const float* __restrict__ x,
                                                     float* __restrict__ out) {
    int tid = blockIdx.x * 256 + threadIdx.x;
    int plane = tid >> 11;                // 2048 threads per plane: 64 row-pairs x 32
    int rem = tid & 2047;
    int h2 = rem >> 5;                    // row-pair index, rows h..h+1
    int lane31 = rem & 31;
    int w0 = lane31 << 2;
    int h = h2 << 1;

    const float* xp = x + (size_t)plane * HWd;

    // 4 input rows h-1..h+2, 4 center cols each, zero-padded rows.
    // Only dr=0 (h-1, h2==0) and dr=3 (h+2, h2==63) can be out of range.
    v4f v[4];
#pragma unroll
    for (int dr = 0; dr < 4; ++dr) {
        int hh = h + dr - 1;
        if (hh < 0 || hh >= Hd) {
            v[dr] = (v4f){0.f, 0.f, 0.f, 0.f};
        } else {
            v[dr] = *reinterpret_cast<const v4f*>(xp + hh * Wd + w0);
        }
    }

    // halo columns from neighbor lanes (convergent). 32 lanes cover one row
    // segment; shfl distance 1 only crosses the half-wave seam at lanes
    // 31/32, which the edge masks (lane31==0 / ==31) discard anyway.
    float r[4][6];
#pragma unroll
    for (int dr = 0; dr < 4; ++dr) {
        float left  = __shfl_up(v[dr].w, 1);
        float right = __shfl_down(v[dr].x, 1);
        r[dr][0] = (lane31 == 0)  ? 0.f : left;
        r[dr][1] = v[dr].x; r[dr][2] = v[dr].y; r[dr][3] = v[dr].z; r[dr][4] = v[dr].w;
        r[dr][5] = (lane31 == 31) ? 0.f : right;
    }

    // column sums for the top (rows 0-2) and bottom (rows 1-3) windows,
    // sharing the middle two rows' terms.
    float colS[2][6], colE[2][6], colN[2][6];
#pragma unroll
    for (int j = 0; j < 6; ++j) {
        float e[4], n[4];
#pragma unroll
        for (int dr = 0; dr < 4; ++dr) {
            float vv = r[dr][j];
            e[dr] = vv * vv;
            float cl = fmaxf(vv, 1e-6f);
            n[dr] = cl * __logf(cl);
        }
        float s12 = r[1][j] + r[2][j];
        float e12 = e[1] + e[2];
        float n12 = n[1] + n[2];
        colS[0][j] = r[0][j] + s12;  colS[1][j] = s12 + r[3][j];
        colE[0][j] = e[0] + e12;     colE[1][j] = e12 + e[3];
        colN[0][j] = n[0] + n12;     colN[1][j] = n12 + n[3];
    }

    size_t base = (size_t)plane * 4 * HWd + h * Wd + w0;

#pragma unroll
    for (int rs = 0; rs < 2; ++rs) {       // rs=0 -> row h, rs=1 -> row h+1
        float con[4], ene[4], ent[4], hom[4];
#pragma unroll
        for (int i = 0; i < 4; ++i) {
            float sum = colS[rs][i] + colS[rs][i + 1] + colS[rs][i + 2];
            float m = sum * (1.f / 9.f);
            float E9 = colE[rs][i] + colE[rs][i + 1] + colE[rs][i + 2];
            float energy = E9 * (1.f / 9.f);
            float entropy = -(colN[rs][i] + colN[rs][i + 1] + colN[rs][i + 2]) * (1.f / 9.f);

            float s2 = fmaxf(fmaf(-m, sum, E9), 0.f);   // sum (v-m)^2

            float sa = 0.f;
#pragma unroll
            for (int dr = 0; dr < 3; ++dr) {
#pragma unroll
                for (int dj = 0; dj < 3; ++dj)
                    sa += fabsf(r[rs + dr][i + dj] - m);
            }
            float var = s2 * 0.125f;                    // ddof=1 -> /8
            float sd = fmaxf(sqrtf(var), 1e-3f);
            float contrast = s2 * (1.f / 9.f) / (sd * sd);
            float homog = 1.f / ((9.f + sa) * (1.f / 9.f) + 1e-6f);

            con[i] = mart(contrast);
            ene[i] = mart(energy);
            ent[i] = mart(entropy);
            hom[i] = mart(homog);
        }
        size_t o = base + rs * Wd;
        __builtin_nontemporal_store((v4f){con[0], con[1], con[2], con[3]},
                                    reinterpret_cast<v4f*>(out + o));
        __builtin_nontemporal_store((v4f){ene[0], ene[1], ene[2], ene[3]},
                                    reinterpret_cast<v4f*>(out + o + HWd));
        __builtin_nontemporal_store((v4f){ent[0], ent[1], ent[2], ent[3]},
                                    reinterpret_cast<v4f*>(out + o + 2 * HWd));
        __builtin_nontemporal_store((v4f){hom[0], hom[1], hom[2], hom[3]},
                                    reinterpret_cast<v4f*>(out + o + 3 * HWd));
    }
}

extern "C" void kernel_launch(void* const* d_in, const int* in_sizes, int n_in,
                              void* d_out, int out_size, void* d_ws, size_t ws_size,
                              hipStream_t stream) {
    const float* x = (const float*)d_in[0];
    float* out = (float*)d_out;
    int n_planes = in_sizes[0] / HWd;            // B*C = 512
    int total_threads = n_planes * (HWd / 8);    // 8 px per thread
    int blocks = total_threads / 256;            // exact: 4096
    medseg_kernel<<<blocks, 256, 0, stream>>>(x, out);
}